// Round 4
// baseline (319.361 us; speedup 1.0000x reference)
//
#include <hip/hip_runtime.h>
#include <math.h>

// InvariantPointAttention — MI355X fp32, round 4: register-resident accumulators,
// k-outer loops, streaming layouts. B=1 assumed.
#define N     384
#define DSd   384
#define DP    128
#define DH    16
#define H     12
#define PQK   4
#define PV    8
#define HC    (H*DH)          // 192
#define PROJW 1152
#define NN    (N*N)           // 147456
#define COUTD 2112
#define KSPL  4
#define KCH   96              // N / KSPL

// ---------------------------------------------------------------------------
__global__ __launch_bounds__(256) void pack_w(
    const float* __restrict__ Wq, const float* __restrict__ Wkv,
    const float* __restrict__ Wqp, const float* __restrict__ Wkvp,
    const float* __restrict__ bq, const float* __restrict__ bkv,
    const float* __restrict__ bqp, const float* __restrict__ bkvp,
    float* __restrict__ Wcat, float* __restrict__ bcat)
{
    const int i = blockIdx.x * 256 + threadIdx.x;
    if (i < DSd * PROJW) {
        const int r = i / PROJW, c = i % PROJW;
        float v;
        if (c < 192)      v = Wq[r*192 + c];
        else if (c < 576) v = Wkv[r*384 + (c-192)];
        else if (c < 720) v = Wqp[r*144 + (c-576)];
        else              v = Wkvp[r*432 + (c-720)];
        Wcat[i] = v;
    }
    if (i < PROJW) {
        float v;
        if (i < 192)      v = bq[i];
        else if (i < 576) v = bkv[i-192];
        else if (i < 720) v = bqp[i-576];
        else              v = bkvp[i-720];
        bcat[i] = v;
    }
}

// ---------------------------------------------------------------------------
// 32x64-tile fp32 GEMM with split-K; writes raw partials partial[z][M][Nc].
__global__ __launch_bounds__(256) void gemm32x64(
    const float* __restrict__ A, const float* __restrict__ B,
    float* __restrict__ partial, int M, int Nc, int K, int kchunk)
{
    __shared__ float Ast[32][34];
    __shared__ float Bs[32][68];
    const int tid = threadIdx.x;
    const int tc = tid & 15, tr = tid >> 4;
    const int row0 = blockIdx.x * 32, col0 = blockIdx.y * 64;
    const int kbeg = blockIdx.z * kchunk;
    const int kend = kbeg + kchunk;
    float acc[2][4] = {};

    for (int kk = kbeg; kk < kend; kk += 32) {
        #pragma unroll
        for (int i = tid; i < 32*32; i += 256) {
            int r = i >> 5, c = i & 31;
            Ast[c][r] = A[(row0 + r) * K + kk + c];
        }
        #pragma unroll
        for (int i = tid; i < 32*64; i += 256) {
            int r = i >> 6, c = i & 63;
            Bs[r][c] = B[(kk + r) * Nc + col0 + c];
        }
        __syncthreads();
        #pragma unroll
        for (int p = 0; p < 32; ++p) {
            const float2 av = *(const float2*)&Ast[p][tr*2];
            const float4 bv = *(const float4*)&Bs[p][tc*4];
            acc[0][0] = fmaf(av.x, bv.x, acc[0][0]);
            acc[0][1] = fmaf(av.x, bv.y, acc[0][1]);
            acc[0][2] = fmaf(av.x, bv.z, acc[0][2]);
            acc[0][3] = fmaf(av.x, bv.w, acc[0][3]);
            acc[1][0] = fmaf(av.y, bv.x, acc[1][0]);
            acc[1][1] = fmaf(av.y, bv.y, acc[1][1]);
            acc[1][2] = fmaf(av.y, bv.z, acc[1][2]);
            acc[1][3] = fmaf(av.y, bv.w, acc[1][3]);
        }
        __syncthreads();
    }
    float* p0 = partial + ((size_t)blockIdx.z * M + row0 + tr*2) * Nc + col0 + tc*4;
    *(float4*)p0        = make_float4(acc[0][0], acc[0][1], acc[0][2], acc[0][3]);
    *(float4*)(p0 + Nc) = make_float4(acc[1][0], acc[1][1], acc[1][2], acc[1][3]);
}

__global__ __launch_bounds__(256) void reduce_kernel(
    const float* __restrict__ partial, const float* __restrict__ bias,
    float* __restrict__ out, int nc, int parts, int stride)
{
    const int i = blockIdx.x * 256 + threadIdx.x;
    float a = bias[i % nc];
    for (int t = 0; t < parts; ++t) a += partial[(size_t)t * stride + i];
    out[i] = a;
}

// ---------------------------------------------------------------------------
// Repack projections + frame rotation.
// vcat layout: (h, j, n) with j in [0,40): j<16 -> v[d=j]; j>=16 -> v_pts
// component (pt-4)*3+axis. k-contiguous for streaming in opair part 2.
__global__ __launch_bounds__(192) void repack_kernel(
    const float* __restrict__ proj, const float* __restrict__ rot,
    const float* __restrict__ trans,
    float* __restrict__ q_t, float* __restrict__ k_t, float* __restrict__ vcat,
    float* __restrict__ qpts_t, float* __restrict__ kpts_t)
{
    const int n = blockIdx.x;
    const int tid = threadIdx.x;
    const float* pr = proj + n * PROJW;

    {
        int h = tid >> 4, d = tid & 15;
        q_t[(h*N + n)*DH + d]     = pr[h*DH + d];
        k_t[(h*N + n)*DH + d]     = pr[HC + h*2*DH + d];
        vcat[(h*40 + d)*N + n]    = pr[HC + h*2*DH + DH + d];
    }
    const float r00 = rot[n*9+0], r01 = rot[n*9+1], r02 = rot[n*9+2];
    const float r10 = rot[n*9+3], r11 = rot[n*9+4], r12 = rot[n*9+5];
    const float r20 = rot[n*9+6], r21 = rot[n*9+7], r22 = rot[n*9+8];
    const float t0 = trans[n*3+0], t1 = trans[n*3+1], t2 = trans[n*3+2];

    if (tid < H*PQK) {
        int p = tid;
        float l0 = pr[576 + 0*48 + p];
        float l1 = pr[576 + 1*48 + p];
        float l2 = pr[576 + 2*48 + p];
        int h = p / PQK, pt = p % PQK;
        float* dst = qpts_t + (h*N + n)*12 + pt*3;
        dst[0] = r00*l0 + r01*l1 + r02*l2 + t0;
        dst[1] = r10*l0 + r11*l1 + r12*l2 + t1;
        dst[2] = r20*l0 + r21*l1 + r22*l2 + t2;
    }
    if (tid < H*(PQK+PV)) {
        int p = tid;
        float l0 = pr[720 + 0*144 + p];
        float l1 = pr[720 + 1*144 + p];
        float l2 = pr[720 + 2*144 + p];
        int h = p / 12, pt = p % 12;
        float x0 = r00*l0 + r01*l1 + r02*l2 + t0;
        float x1 = r10*l0 + r11*l1 + r12*l2 + t1;
        float x2 = r20*l0 + r21*l1 + r22*l2 + t2;
        if (pt < PQK) {
            float* dst = kpts_t + (h*N + n)*12 + pt*3;
            dst[0] = x0; dst[1] = x1; dst[2] = x2;
        } else {
            const int j = 16 + (pt - PQK)*3;
            vcat[(h*40 + j+0)*N + n] = x0;
            vcat[(h*40 + j+1)*N + n] = x1;
            vcat[(h*40 + j+2)*N + n] = x2;
        }
    }
}

// ---------------------------------------------------------------------------
// bias_t[h][pair] = (z[pair,:] . Wb[:,h] + bb[h]) * sqrt(1/3), stored (H,N,N).
// One thread per pair; float4 z loads; 12 register accumulators; Wb via s_load.
__global__ __launch_bounds__(256) void bias_kernel(
    const float* __restrict__ z, const float* __restrict__ Wb,
    const float* __restrict__ bb, float* __restrict__ biasattn)
{
    const int pair = blockIdx.x * 256 + threadIdx.x;   // grid exactly NN
    const float4* zp = (const float4*)(z + (size_t)pair * DP);
    float acc[12] = {};
    #pragma unroll 4
    for (int c4 = 0; c4 < DP/4; ++c4) {
        const float4 zv = zp[c4];
        #pragma unroll
        for (int h = 0; h < H; ++h) {
            acc[h] = fmaf(zv.x, Wb[(c4*4+0)*H + h], acc[h]);
            acc[h] = fmaf(zv.y, Wb[(c4*4+1)*H + h], acc[h]);
            acc[h] = fmaf(zv.z, Wb[(c4*4+2)*H + h], acc[h]);
            acc[h] = fmaf(zv.w, Wb[(c4*4+3)*H + h], acc[h]);
        }
    }
    const float sc = 0.5773502691896258f;              // sqrt(1/3)
    #pragma unroll
    for (int h = 0; h < H; ++h)
        biasattn[h*NN + pair] = (acc[h] + bb[h]) * sc;
}

// ---------------------------------------------------------------------------
__global__ __launch_bounds__(128) void attn_kernel(
    const float* __restrict__ q_t, const float* __restrict__ k_t,
    const float* __restrict__ qpts_t, const float* __restrict__ kpts_t,
    const float* __restrict__ mask, const float* __restrict__ head_weights,
    float* __restrict__ biasattn)
{
    const int h  = blockIdx.x % H;
    const int qi = blockIdx.x / H;
    const int tid = threadIdx.x;
    __shared__ float logits[N];
    __shared__ float red[4];

    const float4* qv = (const float4*)(q_t + (h*N + qi)*DH);
    const float4 q0 = qv[0], q1 = qv[1], q2 = qv[2], q3 = qv[3];
    const float4* qpv = (const float4*)(qpts_t + (h*N + qi)*12);
    const float4 p0 = qpv[0], p1 = qpv[1], p2 = qpv[2];
    const float hw = log1pf(expf(head_weights[h])) * 0.13608276348795434f; // sqrt(1/54)

    float lmax = -1e30f;
    for (int k = tid; k < N; k += 128) {
        const float4* kr = (const float4*)(k_t + (h*N + k)*DH);
        const float4 a0 = kr[0], a1 = kr[1], a2 = kr[2], a3 = kr[3];
        float dot = q0.x*a0.x;
        dot = fmaf(q0.y, a0.y, dot); dot = fmaf(q0.z, a0.z, dot); dot = fmaf(q0.w, a0.w, dot);
        dot = fmaf(q1.x, a1.x, dot); dot = fmaf(q1.y, a1.y, dot); dot = fmaf(q1.z, a1.z, dot); dot = fmaf(q1.w, a1.w, dot);
        dot = fmaf(q2.x, a2.x, dot); dot = fmaf(q2.y, a2.y, dot); dot = fmaf(q2.z, a2.z, dot); dot = fmaf(q2.w, a2.w, dot);
        dot = fmaf(q3.x, a3.x, dot); dot = fmaf(q3.y, a3.y, dot); dot = fmaf(q3.z, a3.z, dot); dot = fmaf(q3.w, a3.w, dot);
        const float4* kp = (const float4*)(kpts_t + (h*N + k)*12);
        const float4 b0 = kp[0], b1 = kp[1], b2 = kp[2];
        float df, d2;
        df = p0.x-b0.x; d2 = df*df;
        df = p0.y-b0.y; d2 = fmaf(df, df, d2);
        df = p0.z-b0.z; d2 = fmaf(df, df, d2);
        df = p0.w-b0.w; d2 = fmaf(df, df, d2);
        df = p1.x-b1.x; d2 = fmaf(df, df, d2);
        df = p1.y-b1.y; d2 = fmaf(df, df, d2);
        df = p1.z-b1.z; d2 = fmaf(df, df, d2);
        df = p1.w-b1.w; d2 = fmaf(df, df, d2);
        df = p2.x-b2.x; d2 = fmaf(df, df, d2);
        df = p2.y-b2.y; d2 = fmaf(df, df, d2);
        df = p2.z-b2.z; d2 = fmaf(df, df, d2);
        df = p2.w-b2.w; d2 = fmaf(df, df, d2);
        float l = fmaf(dot, 0.14433756729740643f,
                       biasattn[h*NN + qi*N + k] + mask[qi*N + k])
                - 0.5f * hw * d2;
        logits[k] = l;
        lmax = fmaxf(lmax, l);
    }
    #pragma unroll
    for (int o = 32; o > 0; o >>= 1) lmax = fmaxf(lmax, __shfl_xor(lmax, o));
    if ((tid & 63) == 0) red[tid >> 6] = lmax;
    __syncthreads();
    const float m = fmaxf(red[0], red[1]);
    float lsum = 0.f;
    for (int k = tid; k < N; k += 128) {
        float e = __expf(logits[k] - m);
        logits[k] = e;
        lsum += e;
    }
    #pragma unroll
    for (int o = 32; o > 0; o >>= 1) lsum += __shfl_xor(lsum, o);
    if ((tid & 63) == 0) red[2 + (tid >> 6)] = lsum;
    __syncthreads();
    const float inv = 1.f / (red[2] + red[3]);
    for (int k = tid; k < N; k += 128)
        biasattn[h*NN + qi*N + k] = logits[k] * inv;
}

// ---------------------------------------------------------------------------
// Split-k output accumulation. Block (qi, kq) covers k in [kq*96, kq*96+96).
// Part 1 (o_pair): k-outer, 12 head-accumulators in registers, one coalesced
// z load per k, attn via wave-uniform s_load broadcast.
// Part 2 (o/o_pts): lane j<40 streams contiguous vcat rows, 3 chains per wave.
__global__ __launch_bounds__(256) void opair_partial(
    const float* __restrict__ attn, const float* __restrict__ vcat,
    const float* __restrict__ z, float* __restrict__ P1, float* __restrict__ P2)
{
    const int qi = blockIdx.x, kq = blockIdx.y;
    const int k0 = kq * KCH;
    const int tid = threadIdx.x;
    __shared__ float pzs[2][H][DP];   // 12 KB

    {   // o_pair: lane owns channel c; wave-pair owns 48 of the 96 k's
        const int c = tid & 127;
        const int half = __builtin_amdgcn_readfirstlane(tid >> 7);
        const float* zp = z + ((size_t)qi*N + k0 + half*48)*DP + c;
        const float* arow = attn + qi*N + k0 + half*48;   // + h*NN (uniform)
        float acc[12] = {};
        #pragma unroll 4
        for (int k = 0; k < 48; ++k) {
            const float zv = zp[(size_t)k*DP];            // 256B/wave, coalesced
            #pragma unroll
            for (int h = 0; h < H; ++h)
                acc[h] = fmaf(arow[h*NN + k], zv, acc[h]); // s_load broadcast
        }
        #pragma unroll
        for (int h = 0; h < H; ++h) pzs[half][h][c] = acc[h];
    }
    {   // o (16) + o_pts (24): wave -> 3 heads, lanes 0..39 stream k-contiguous
        const int wv = __builtin_amdgcn_readfirstlane(tid >> 6);
        const int lane = tid & 63;
        if (lane < 40) {
            const int h0 = wv*3;
            const float* a0 = attn + (h0+0)*NN + qi*N + k0;   // uniform
            const float* a1 = attn + (h0+1)*NN + qi*N + k0;
            const float* a2 = attn + (h0+2)*NN + qi*N + k0;
            const float* v0 = vcat + ((h0+0)*40 + lane)*N + k0;
            const float* v1 = vcat + ((h0+1)*40 + lane)*N + k0;
            const float* v2 = vcat + ((h0+2)*40 + lane)*N + k0;
            float s0 = 0.f, s1 = 0.f, s2 = 0.f;
            #pragma unroll 4
            for (int k = 0; k < KCH; ++k) {
                s0 = fmaf(a0[k], v0[k], s0);
                s1 = fmaf(a1[k], v1[k], s1);
                s2 = fmaf(a2[k], v2[k], s2);
            }
            float* pb = P1 + ((size_t)qi*KSPL + kq)*480;
            const int j0 = (lane < 16) ? (h0+0)*16 + lane : 192 + (h0+0)*24 + (lane-16);
            const int j1 = (lane < 16) ? (h0+1)*16 + lane : 192 + (h0+1)*24 + (lane-16);
            const int j2 = (lane < 16) ? (h0+2)*16 + lane : 192 + (h0+2)*24 + (lane-16);
            pb[j0] = s0; pb[j1] = s1; pb[j2] = s2;
        }
    }
    __syncthreads();
    for (int i = tid; i < H*DP; i += 256)
        P2[((size_t)qi*KSPL + kq)*(H*DP) + i] = pzs[0][i>>7][i&127] + pzs[1][i>>7][i&127];
}

// ---------------------------------------------------------------------------
// Per-q: sum split-k partials, inverse-frame o_pts + norms, assemble cat row.
__global__ __launch_bounds__(256) void combine_kernel(
    const float* __restrict__ P1, const float* __restrict__ P2,
    const float* __restrict__ rot, const float* __restrict__ trans,
    float* __restrict__ cat)
{
    const int qi = blockIdx.x;
    const int tid = threadIdx.x;
    __shared__ float catv[COUTD];
    __shared__ float praw[H*PV*3];

    for (int j = tid; j < 480; j += 256) {
        const float* p = P1 + (size_t)qi*KSPL*480 + j;
        float s = p[0] + p[480] + p[960] + p[1440];
        if (j < 192) catv[j] = s; else praw[j-192] = s;
    }
    for (int i = tid; i < H*DP; i += 256) {
        const float* p = P2 + (size_t)qi*KSPL*(H*DP) + i;
        catv[576 + i] = p[0] + p[1536] + p[3072] + p[4608];
    }
    __syncthreads();
    if (tid < H*PV) {
        const float* rr = rot + qi*9;
        const float t0 = trans[qi*3+0], t1 = trans[qi*3+1], t2 = trans[qi*3+2];
        float y0 = praw[tid*3+0] - t0;
        float y1 = praw[tid*3+1] - t1;
        float y2 = praw[tid*3+2] - t2;
        float f0 = rr[0]*y0 + rr[3]*y1 + rr[6]*y2;
        float f1 = rr[1]*y0 + rr[4]*y1 + rr[7]*y2;
        float f2 = rr[2]*y0 + rr[5]*y1 + rr[8]*y2;
        catv[HC + 0*96 + tid] = f0;
        catv[HC + 1*96 + tid] = f1;
        catv[HC + 2*96 + tid] = f2;
        catv[HC + 3*96 + tid] = sqrtf(f0*f0 + f1*f1 + f2*f2 + 1e-8f);
    }
    __syncthreads();
    float4* dst = (float4*)(cat + (size_t)qi * COUTD);
    const float4* src = (const float4*)catv;
    for (int i = tid; i < COUTD/4; i += 256) dst[i] = src[i];
}

// ---------------------------------------------------------------------------
extern "C" void kernel_launch(void* const* d_in, const int* in_sizes, int n_in,
                              void* d_out, int out_size, void* d_ws, size_t ws_size,
                              hipStream_t stream)
{
    const float* s       = (const float*)d_in[0];
    const float* z       = (const float*)d_in[1];
    const float* rot     = (const float*)d_in[2];
    const float* trans   = (const float*)d_in[3];
    const float* mask    = (const float*)d_in[4];
    const float* Wq      = (const float*)d_in[5];
    const float* bq      = (const float*)d_in[6];
    const float* Wkv     = (const float*)d_in[7];
    const float* bkv     = (const float*)d_in[8];
    const float* Wq_pts  = (const float*)d_in[9];
    const float* bq_pts  = (const float*)d_in[10];
    const float* Wkv_pts = (const float*)d_in[11];
    const float* bkv_pts = (const float*)d_in[12];
    const float* Wb      = (const float*)d_in[13];
    const float* bb      = (const float*)d_in[14];
    const float* hwts    = (const float*)d_in[15];
    const float* Wout    = (const float*)d_in[16];
    const float* bout    = (const float*)d_in[17];
    float* out = (float*)d_out;
    float* ws  = (float*)d_ws;

    // ---- workspace layout (floats) ----
    float* ba     = ws;                    // 1,769,472  (bias -> attn in place)
    float* cat    = ba     + 1769472;      //   811,008
    float* q_t    = cat    + 811008;       //    73,728
    float* k_t    = q_t    + 73728;        //    73,728
    float* qpts_t = k_t    + 73728;        //    55,296
    float* kpts_t = qpts_t + 55296;        //    55,296
    float* vcat   = kpts_t + 55296;        //   184,320  (H,40,N)
    float* X      = vcat   + 184320;       // shared region
    // early phase:
    float* proj     = X;                   //   442,368
    float* partialP = X + 442368;          //   884,736
    float* Wcat     = X + 1327104;         //   442,368
    float* bcat     = X + 1769472;         //     1,152
    // late phase:
    float* P1       = X;                   //   737,280
    float* P2       = X + 737280;          // 2,359,296
    float* partialF = X;                   // 1,622,016 (after combine)

    pack_w<<<1728, 256, 0, stream>>>(Wq, Wkv, Wq_pts, Wkv_pts, bq, bkv, bq_pts, bkv_pts, Wcat, bcat);
    gemm32x64<<<dim3(12,18,2), 256, 0, stream>>>(s, Wcat, partialP, N, PROJW, DSd, 192);
    reduce_kernel<<<1728, 256, 0, stream>>>(partialP, bcat, proj, PROJW, 2, 442368);
    repack_kernel<<<N, 192, 0, stream>>>(proj, rot, trans, q_t, k_t, vcat, qpts_t, kpts_t);
    bias_kernel<<<NN/256, 256, 0, stream>>>(z, Wb, bb, ba);
    attn_kernel<<<N*H, 128, 0, stream>>>(q_t, k_t, qpts_t, kpts_t, mask, hwts, ba);
    opair_partial<<<dim3(N, KSPL), 256, 0, stream>>>(ba, vcat, z, P1, P2);
    combine_kernel<<<N, 256, 0, stream>>>(P1, P2, rot, trans, cat);
    gemm32x64<<<dim3(12,6,11), 256, 0, stream>>>(cat, Wout, partialF, N, 384, COUTD, 192);
    reduce_kernel<<<576, 256, 0, stream>>>(partialF, bout, out, 384, 11, NN);
}